// Round 16
// baseline (200.416 us; speedup 1.0000x reference)
//
#include <hip/hip_runtime.h>

#define NCH 128
#define TILE 2048     // edges per block in partition kernel (782 blocks -> ~3/CU)
#define SUBCAP 3072   // slack per (xcd,bucket) region; mean ~781
#define SCHUNK 2048   // edges staged in LDS per chunk in sage (u32 -> 8KB)
#define SNODES 32     // dst nodes per sage block
#define HSTRIDE 264   // ushorts per LDS row: 256 + 8 pad (528B, 16B-aligned)

typedef __attribute__((ext_vector_type(8))) short bf16x8;
typedef __attribute__((ext_vector_type(4))) float f32x4;
typedef __attribute__((ext_vector_type(2))) _Float16 half2f;  // fdot2 operand type
typedef __attribute__((ext_vector_type(2))) __fp16  half2h;   // cvt_pkrtz result type

__device__ inline unsigned short f2bf(float f) {
  unsigned int u = __builtin_bit_cast(unsigned int, f);
  unsigned int r = u + 0x7fffu + ((u >> 16) & 1u);
  return (unsigned short)(r >> 16);
}

// Physical XCD id (0..7, wave-uniform; block runs on one CU -> one XCD).
__device__ inline int xcc_id() {
  int x;
  asm volatile("s_getreg_b32 %0, hwreg(HW_REG_XCC_ID)" : "=s"(x));
  return x & 7;
}

// pack two floats to f16x2 in a u32 (v_cvt_pkrtz_f16_f32)
__device__ inline unsigned int pack_f16(float a, float b) {
  half2h p = __builtin_amdgcn_cvt_pkrtz(a, b);
  return __builtin_bit_cast(unsigned int, p);
}

// z = t.x*w.x + t.y*w.y + acc  (one v_dot2_f32_f16 when available)
__device__ inline float dot2_acc(unsigned int tpk, unsigned int wpk, float acc) {
#if __has_builtin(__builtin_amdgcn_fdot2)
  return __builtin_amdgcn_fdot2(__builtin_bit_cast(half2f, tpk),
                                __builtin_bit_cast(half2f, wpk), acc, false);
#else
  half2h t = __builtin_bit_cast(half2h, tpk);
  half2h w = __builtin_bit_cast(half2h, wpk);
  return fmaf((float)t.x, (float)w.x, fmaf((float)t.y, (float)w.y, acc));
#endif
}

// Weight packing into MFMA B-fragment order + misc init (gcur, out).
__global__ void prep_w_kernel(const float* __restrict__ Wl, const float* __restrict__ Wr,
                              const float* __restrict__ Wv1,
                              unsigned short* fw1, unsigned short* fw2,
                              int* __restrict__ gcur1, int* __restrict__ gcur2,
                              float* out, const float* __restrict__ bv2, int n) {
  int i = blockIdx.x * blockDim.x + threadIdx.x;
  if (i < 32768) {
    int j = i & 7, l = (i >> 3) & 63, s = (i >> 9) & 7, t = i >> 12;
    int k = s * 32 + (l >> 4) * 8 + j;
    int nn = t * 16 + (l & 15);
    float v = (k < 128) ? Wl[k * 128 + nn] : Wr[(k - 128) * 128 + nn];
    fw1[i] = f2bf(v);
  }
  if (i < 8192) {
    int j = i & 7, l = (i >> 3) & 63, s = (i >> 9) & 3, t = i >> 11;
    int k = s * 32 + (l >> 4) * 8 + j;
    int nn = t * 16 + (l & 15);
    fw2[i] = f2bf(Wv1[k * 64 + nn]);
  }
  if (i < 2048) gcur1[i] = i * SUBCAP;           // (xcd*256+bin) region bases
  else if (i < 4096) gcur2[i - 2048] = (i - 2048) * SUBCAP;
  if (i == 4096) out[0] = (float)n * bv2[0];
}

// Single-pass coarse partition with XCD-private bucket regions (R11: keeps
// partial-line stores merging in the local L2; cross-XCD sharing caused 4x
// write-through amplification).
__global__ __launch_bounds__(256) void partition_kernel(
    const int* __restrict__ src, const int* __restrict__ dst,
    int* __restrict__ gcur1, int* __restrict__ gcur2,
    unsigned int* __restrict__ part, unsigned short* __restrict__ part_s, int ne) {
  __shared__ int h1[256], h2[256], c1[256], c2[256];
  int t = threadIdx.x, b = blockIdx.x;
  h1[t] = 0; h2[t] = 0;
  __syncthreads();
  int base = b * TILE;
  int lim = min(base + TILE, ne);
  for (int i = base + t; i < lim; i += 256) {
    atomicAdd(&h1[((unsigned)dst[i]) >> 8], 1);
    atomicAdd(&h2[((unsigned)src[i]) >> 8], 1);
  }
  __syncthreads();
  int xcd = xcc_id();
  c1[t] = atomicAdd(&gcur1[xcd * 256 + t], h1[t]);
  c2[t] = atomicAdd(&gcur2[xcd * 256 + t], h2[t]);
  __syncthreads();
  for (int i = base + t; i < lim; i += 256) {
    unsigned d = (unsigned)dst[i], s = (unsigned)src[i];
    int p1 = atomicAdd(&c1[d >> 8], 1);
    part[p1] = (d << 16) | s;
    int p2 = atomicAdd(&c2[s >> 8], 1);
    part_s[p2] = (unsigned short)s;
  }
}

// Split bucket pass (512 blocks = 2/CU): b<256 dst side (indeg/deg/row_beg,
// csr scatter at dense base b*8192); b>=256 src side (outdeg hist).
__global__ __launch_bounds__(256) void bucket_kernel(
    const unsigned int* __restrict__ part, const unsigned short* __restrict__ part_s,
    const int* __restrict__ gcur1, const int* __restrict__ gcur2,
    int* __restrict__ row_beg, int* __restrict__ deg, int* __restrict__ csr_src,
    int* __restrict__ outdeg, int n) {
  __shared__ int h[256], sc[256], c[256];
  int t = threadIdx.x;
  int b = blockIdx.x;
  h[t] = 0;
  __syncthreads();
  if (b < 256) {
#pragma unroll
    for (int xz = 0; xz < 8; xz++) {
      int rb = (xz * 256 + b) * SUBCAP, re = gcur1[xz * 256 + b];
      for (int i = rb + t; i < re; i += 256)
        atomicAdd(&h[(part[i] >> 16) & 255], 1);
    }
    __syncthreads();
    int hv = h[t];
    sc[t] = hv;
    __syncthreads();
    for (int off = 1; off < 256; off <<= 1) {
      int u = (t >= off) ? sc[t - off] : 0;
      __syncthreads();
      sc[t] += u;
      __syncthreads();
    }
    int bucketBase = b * 8192;
    int excl = sc[t] - hv;
    int node = b * 256 + t;
    if (node < n) { row_beg[node] = bucketBase + excl; deg[node] = hv; }
    c[t] = bucketBase + excl;
    __syncthreads();
#pragma unroll
    for (int xz = 0; xz < 8; xz++) {
      int rb = (xz * 256 + b) * SUBCAP, re = gcur1[xz * 256 + b];
      for (int i = rb + t; i < re; i += 256) {
        unsigned key = part[i];
        int pos = atomicAdd(&c[(key >> 16) & 255], 1);
        csr_src[pos] = (int)(key & 0xFFFFu);
      }
    }
  } else {
    int bs = b - 256;
#pragma unroll
    for (int xz = 0; xz < 8; xz++) {
      int sb = (xz * 256 + bs) * SUBCAP, se = gcur2[xz * 256 + bs];
      for (int i = sb + t; i < se; i += 256)
        atomicAdd(&h[part_s[i] & 255], 1);
    }
    __syncthreads();
    int node = bs * 256 + t;
    if (node < n) outdeg[node] = h[t];
  }
}

// p2[i] = rsqrt(indeg+1) * [x_i, outdeg_i]
__global__ void p2_kernel(const float* __restrict__ x, const int* __restrict__ outdeg,
                          const int* __restrict__ deg, float* __restrict__ p2, int n) {
  int i = blockIdx.x * blockDim.x + threadIdx.x;
  if (i < n) {
    float dinv = rsqrtf((float)deg[i] + 1.0f);
    p2[2 * i]     = dinv * x[i];
    p2[2 * i + 1] = dinv * (float)outdeg[i];
  }
}

// GCN aggregate in 2-dim space: t[d] = dinv*(sum_in dinv[s]*xin[s] + self).
// 16 lanes per node, 4 nodes/wave. tvec stored as packed f16x2 (u32) for the
// downstream fdot2 consumers (f16 mantissa > bf16 used elsewhere; |t|~O(4)).
__global__ __launch_bounds__(256) void gcn_t_kernel(
    const int* __restrict__ row_beg, const int* __restrict__ deg,
    const int* __restrict__ csr_src,
    const float* __restrict__ p2, unsigned int* __restrict__ tvec, int npad, int n) {
  int tid = threadIdx.x;
  int lane = tid & 63;
  int sl = lane & 15, g = lane >> 4;
  int wid = blockIdx.x * 16 + (tid >> 6) * 4 + g;
  if (wid >= npad) return;
  int beg = 0, dg = 0;
  if (wid < n) { beg = row_beg[wid]; dg = deg[wid]; }
  float s0 = 0.0f, s1 = 0.0f;
  for (int k = beg + sl; k < beg + dg; k += 16) {
    int s = csr_src[k];
    float2 v = *reinterpret_cast<const float2*>(p2 + 2 * (size_t)s);
    s0 += v.x; s1 += v.y;
  }
#pragma unroll
  for (int off = 1; off < 16; off <<= 1) {
    s0 += __shfl_xor(s0, off, 64);
    s1 += __shfl_xor(s1, off, 64);
  }
  if (sl == 0) {
    if (wid < n) {
      float dinv = rsqrtf((float)dg + 1.0f);
      float2 self = *reinterpret_cast<const float2*>(p2 + 2 * (size_t)wid);
      tvec[wid] = pack_f16(dinv * (s0 + self.x), dinv * (s1 + self.y));
    } else {
      tvec[wid] = 0u;
    }
  }
}

// SAGE mean, two-phase: block = 32 dst nodes. Phase A: lane-parallel gather of
// packed-f16 t pairs into LDS (4B each). Phase B: wave w owns 8 nodes; lane
// owns channels 2l,2l+1; z = v_dot2_f32_f16(t, w) + b (1 inst for the 2-d
// dot), relu, fp32 register accumulate. ~6.5 wave-inst/edge vs 8.5 with fmaf.
__global__ __launch_bounds__(256) void sage_kernel(
    const int* __restrict__ row_beg, const int* __restrict__ deg,
    const int* __restrict__ csr_src, const unsigned int* __restrict__ tvec,
    const float* __restrict__ Wg, const float* __restrict__ bg,
    unsigned int* __restrict__ agg32, int n) {
  __shared__ unsigned int sE[SCHUNK];
  __shared__ int sR[SNODES + 1];
  int tid = threadIdx.x, lane = tid & 63, w = tid >> 6;
  int node0 = blockIdx.x * SNODES;
  if (tid <= SNODES) {
    int node = node0 + tid;
    int v;
    if (tid == SNODES) {
      int last = min(node, n) - 1;
      v = (last >= 0) ? row_beg[last] + deg[last] : 0;
    } else if (node < n) {
      v = row_beg[node];
    } else {
      v = (n > 0) ? row_beg[n - 1] + deg[n - 1] : 0;
    }
    sR[tid] = v;
  }
  __syncthreads();
  int base = sR[0], endAll = sR[SNODES];

  int c0 = 2 * lane, c1 = c0 + 1;
  unsigned int w0pk = pack_f16(Wg[c0], Wg[NCH + c0]);
  unsigned int w1pk = pack_f16(Wg[c1], Wg[NCH + c1]);
  float b0 = bg[c0], b1 = bg[c1];
  float ax[8], ay[8];
#pragma unroll
  for (int i = 0; i < 8; i++) { ax[i] = 0.f; ay[i] = 0.f; }

  for (int cbeg = base; cbeg < endAll; cbeg += SCHUNK) {
    int cend = min(cbeg + SCHUNK, endAll);
    __syncthreads();
    for (int k = cbeg + tid; k < cend; k += 256)
      sE[k - cbeg] = tvec[csr_src[k]];
    __syncthreads();
#pragma unroll
    for (int i = 0; i < 8; i++) {
      int nd = w * 8 + i;
      int rb = max(sR[nd], cbeg) - cbeg;
      int re = min(sR[nd + 1], cend) - cbeg;
      int k = rb;
      for (; k + 3 < re; k += 4) {
        unsigned int tA = sE[k], tB = sE[k + 1], tC = sE[k + 2], tD = sE[k + 3];
        float zA0 = fmaxf(dot2_acc(tA, w0pk, b0), 0.f);
        float zB0 = fmaxf(dot2_acc(tB, w0pk, b0), 0.f);
        float zC0 = fmaxf(dot2_acc(tC, w0pk, b0), 0.f);
        float zD0 = fmaxf(dot2_acc(tD, w0pk, b0), 0.f);
        ax[i] += (zA0 + zB0) + (zC0 + zD0);
        float zA1 = fmaxf(dot2_acc(tA, w1pk, b1), 0.f);
        float zB1 = fmaxf(dot2_acc(tB, w1pk, b1), 0.f);
        float zC1 = fmaxf(dot2_acc(tC, w1pk, b1), 0.f);
        float zD1 = fmaxf(dot2_acc(tD, w1pk, b1), 0.f);
        ay[i] += (zA1 + zB1) + (zC1 + zD1);
      }
      for (; k < re; k++) {
        unsigned int tA = sE[k];
        ax[i] += fmaxf(dot2_acc(tA, w0pk, b0), 0.f);
        ay[i] += fmaxf(dot2_acc(tA, w1pk, b1), 0.f);
      }
    }
  }
#pragma unroll
  for (int i = 0; i < 8; i++) {
    int nd = w * 8 + i;
    int cnt = sR[nd + 1] - sR[nd];
    float inv = 1.0f / (float)(cnt > 1 ? cnt : 1);
    agg32[(size_t)(node0 + nd) * 64 + lane] =
        (unsigned int)f2bf(ax[i] * inv) | ((unsigned int)f2bf(ay[i] * inv) << 16);
  }
}

// MFMA head: A = [agg | a1] (a1 recomputed from packed-f16 t in LDS), K=256
// GEMM vs [Wl;Wr], bias, bf16, K=128 GEMM vs Wv1, relu, dot Wv2, reduce-sum.
__global__ __launch_bounds__(256) void head_kernel(
    const unsigned short* __restrict__ agg, const unsigned int* __restrict__ tvec,
    const float* __restrict__ Wg, const float* __restrict__ bg,
    const unsigned short* __restrict__ fw1, const unsigned short* __restrict__ fw2,
    const float* __restrict__ bl, const float* __restrict__ bv1,
    const float* __restrict__ Wv2, float* __restrict__ out, int n) {
  __shared__ __align__(16) unsigned short sA[64 * HSTRIDE];  // 33 KB
  __shared__ unsigned int sTp[64];
  __shared__ float sRed[4];
  int tid = threadIdx.x;
  int lane = tid & 63;
  int w = tid >> 6;
  int m16 = lane & 15;
  int quad = lane >> 4;
  int node0 = blockIdx.x * 64;

  const uint4* g = reinterpret_cast<const uint4*>(agg + (size_t)node0 * NCH);
  for (int c = tid; c < 1024; c += 256) {
    int row = c >> 4, off = c & 15;
    *reinterpret_cast<uint4*>(&sA[row * HSTRIDE + off * 8]) = g[row * 16 + off];
  }
  if (tid < 64) sTp[tid] = tvec[node0 + tid];
  __syncthreads();

  {
    int cp = tid & 63, r0 = tid >> 6;
    int c0 = 2 * cp, c1 = c0 + 1;
    float w00 = Wg[c0], w10 = Wg[NCH + c0], b0 = bg[c0];
    float w01 = Wg[c1], w11 = Wg[NCH + c1], b1 = bg[c1];
#pragma unroll
    for (int i = 0; i < 16; i++) {
      int row = r0 + 4 * i;
      half2h h = __builtin_bit_cast(half2h, sTp[row]);
      float t0 = (float)h.x, t1 = (float)h.y;
      float z0 = fmaxf(fmaf(t0, w00, fmaf(t1, w10, b0)), 0.f);
      float z1 = fmaxf(fmaf(t0, w01, fmaf(t1, w11, b1)), 0.f);
      *reinterpret_cast<unsigned int*>(&sA[row * HSTRIDE + 128 + 2 * cp]) =
          (unsigned int)f2bf(z0) | ((unsigned int)f2bf(z1) << 16);
    }
  }

  bf16x8 b1f[2][8];
  const bf16x8* f1 = reinterpret_cast<const bf16x8*>(fw1);
#pragma unroll
  for (int p = 0; p < 2; p++)
#pragma unroll
    for (int s = 0; s < 8; s++)
      b1f[p][s] = f1[((w * 2 + p) * 8 + s) * 64 + lane];

  f32x4 acc[4][2];
#pragma unroll
  for (int mt = 0; mt < 4; mt++)
#pragma unroll
    for (int p = 0; p < 2; p++) acc[mt][p] = (f32x4)0.0f;

  __syncthreads();

#pragma unroll
  for (int s = 0; s < 8; s++) {
#pragma unroll
    for (int mt = 0; mt < 4; mt++) {
      bf16x8 aF = *reinterpret_cast<const bf16x8*>(
          &sA[(mt * 16 + m16) * HSTRIDE + s * 32 + quad * 8]);
#pragma unroll
      for (int p = 0; p < 2; p++)
        acc[mt][p] = __builtin_amdgcn_mfma_f32_16x16x32_bf16(aF, b1f[p][s],
                                                             acc[mt][p], 0, 0, 0);
    }
  }

  float blv[2];
#pragma unroll
  for (int p = 0; p < 2; p++) blv[p] = bl[(w * 2 + p) * 16 + m16];
  __syncthreads();
#pragma unroll
  for (int mt = 0; mt < 4; mt++)
#pragma unroll
    for (int p = 0; p < 2; p++) {
      int col = (w * 2 + p) * 16 + m16;
#pragma unroll
      for (int r = 0; r < 4; r++) {
        int row = mt * 16 + quad * 4 + r;
        sA[row * HSTRIDE + col] = f2bf(acc[mt][p][r] + blv[p]);
      }
    }
  __syncthreads();

  bf16x8 b2f[4];
  const bf16x8* f2 = reinterpret_cast<const bf16x8*>(fw2);
#pragma unroll
  for (int s = 0; s < 4; s++) b2f[s] = f2[(w * 4 + s) * 64 + lane];

  f32x4 acc2[4];
#pragma unroll
  for (int mt = 0; mt < 4; mt++) acc2[mt] = (f32x4)0.0f;

#pragma unroll
  for (int s = 0; s < 4; s++) {
#pragma unroll
    for (int mt = 0; mt < 4; mt++) {
      bf16x8 aF = *reinterpret_cast<const bf16x8*>(
          &sA[(mt * 16 + m16) * HSTRIDE + s * 32 + quad * 8]);
      acc2[mt] = __builtin_amdgcn_mfma_f32_16x16x32_bf16(aF, b2f[s], acc2[mt], 0, 0, 0);
    }
  }

  int c2 = w * 16 + m16;
  float bvj = bv1[c2], w2 = Wv2[c2];
  float vsum = 0.0f;
#pragma unroll
  for (int mt = 0; mt < 4; mt++)
#pragma unroll
    for (int r = 0; r < 4; r++) {
      int node = node0 + mt * 16 + quad * 4 + r;
      if (node < n) vsum += fmaxf(acc2[mt][r] + bvj, 0.0f) * w2;
    }
#pragma unroll
  for (int off = 1; off < 64; off <<= 1) vsum += __shfl_xor(vsum, off, 64);
  if (lane == 0) sRed[w] = vsum;
  __syncthreads();
  if (tid == 0) atomicAdd(out, sRed[0] + sRed[1] + sRed[2] + sRed[3]);
}

extern "C" void kernel_launch(void* const* d_in, const int* in_sizes, int n_in,
                              void* d_out, int out_size, void* d_ws, size_t ws_size,
                              hipStream_t stream) {
  const float* x   = (const float*)d_in[0];
  const int*   ei  = (const int*)d_in[1];
  const float* Wg  = (const float*)d_in[2];
  const float* bg  = (const float*)d_in[3];
  const float* Wl  = (const float*)d_in[4];
  const float* bl  = (const float*)d_in[5];
  const float* Wr  = (const float*)d_in[6];
  const float* Wv1 = (const float*)d_in[7];
  const float* bv1 = (const float*)d_in[8];
  const float* Wv2 = (const float*)d_in[9];
  const float* bv2 = (const float*)d_in[10];
  float* out = (float*)d_out;

  int n  = in_sizes[0];
  int E_ = in_sizes[1] / 2;
  int npad = ((n + 63) / 64) * 64;
  int B1 = (E_ + TILE - 1) / TILE;
  const int* src = ei;
  const int* dst = ei + E_;

  // workspace layout (16B alignment per region)
  char* base = (char*)d_ws;
  unsigned short* agg = (unsigned short*)base;  base += (size_t)npad * NCH * 2;   // 12.8MB
  unsigned int* tvec = (unsigned int*)base;     base += (size_t)npad * 4;
  unsigned short* fw1 = (unsigned short*)base;  base += 32768 * 2;
  unsigned short* fw2 = (unsigned short*)base;  base += 8192 * 2;
  float* p2       = (float*)base;               base += (size_t)n * 2 * 4;
  int* gcur1      = (int*)base;                 base += 2048 * 4;
  int* gcur2      = (int*)base;                 base += 2048 * 4;
  unsigned int* part = (unsigned int*)base;     base += (size_t)2048 * SUBCAP * 4;  // 25.2MB
  int* row_beg    = (int*)base;                 base += (size_t)n * 4;
  int* deg        = (int*)base;                 base += (size_t)n * 4;
  int* outdeg     = (int*)base;                 base += (size_t)n * 4;
  int* csr_src    = (int*)base;                 base += (size_t)256 * 8192 * 4;     // 8.4MB
  unsigned short* part_s = (unsigned short*)base;  // 2048*SUBCAP*2 = 12.6MB

  prep_w_kernel<<<128, 256, 0, stream>>>(Wl, Wr, Wv1, fw1, fw2, gcur1, gcur2,
                                         out, bv2, n);
  partition_kernel<<<B1, 256, 0, stream>>>(src, dst, gcur1, gcur2, part, part_s, E_);
  bucket_kernel<<<512, 256, 0, stream>>>(part, part_s, gcur1, gcur2,
                                         row_beg, deg, csr_src, outdeg, n);
  p2_kernel<<<(n + 255) / 256, 256, 0, stream>>>(x, outdeg, deg, p2, n);

  gcn_t_kernel<<<npad / 16, 256, 0, stream>>>(row_beg, deg, csr_src, p2,
                                              tvec, npad, n);
  sage_kernel<<<npad / SNODES, 256, 0, stream>>>(row_beg, deg, csr_src, tvec,
                                                 Wg, bg, (unsigned int*)agg, n);
  head_kernel<<<npad / 64, 256, 0, stream>>>(agg, tvec, Wg, bg, fw1, fw2,
                                             bl, bv1, Wv2, out, n);
}

// Round 17
// 194.708 us; speedup vs baseline: 1.0293x; 1.0293x over previous
//
#include <hip/hip_runtime.h>

#define NCH 128
#define TILE 2048     // edges per block in partition kernel (782 blocks -> ~3/CU)
#define SUBCAP 3072   // slack per (xcd,bucket) region; mean ~781
#define SCHUNK 2048   // edges staged in LDS per chunk in sage
#define SNODES 32     // dst nodes per sage block
#define HSTRIDE 264   // ushorts per LDS row: 256 + 8 pad (528B, 16B-aligned)

typedef __attribute__((ext_vector_type(8))) short bf16x8;
typedef __attribute__((ext_vector_type(4))) float f32x4;

__device__ inline unsigned short f2bf(float f) {
  unsigned int u = __builtin_bit_cast(unsigned int, f);
  unsigned int r = u + 0x7fffu + ((u >> 16) & 1u);
  return (unsigned short)(r >> 16);
}

// Physical XCD id (0..7, wave-uniform; block runs on one CU -> one XCD).
__device__ inline int xcc_id() {
  int x;
  asm volatile("s_getreg_b32 %0, hwreg(HW_REG_XCC_ID)" : "=s"(x));
  return x & 7;
}

// Weight packing into MFMA B-fragment order + misc init (gcur, out).
__global__ void prep_w_kernel(const float* __restrict__ Wl, const float* __restrict__ Wr,
                              const float* __restrict__ Wv1,
                              unsigned short* fw1, unsigned short* fw2,
                              int* __restrict__ gcur1, int* __restrict__ gcur2,
                              float* out, const float* __restrict__ bv2, int n) {
  int i = blockIdx.x * blockDim.x + threadIdx.x;
  if (i < 32768) {
    int j = i & 7, l = (i >> 3) & 63, s = (i >> 9) & 7, t = i >> 12;
    int k = s * 32 + (l >> 4) * 8 + j;
    int nn = t * 16 + (l & 15);
    float v = (k < 128) ? Wl[k * 128 + nn] : Wr[(k - 128) * 128 + nn];
    fw1[i] = f2bf(v);
  }
  if (i < 8192) {
    int j = i & 7, l = (i >> 3) & 63, s = (i >> 9) & 3, t = i >> 11;
    int k = s * 32 + (l >> 4) * 8 + j;
    int nn = t * 16 + (l & 15);
    fw2[i] = f2bf(Wv1[k * 64 + nn]);
  }
  if (i < 2048) gcur1[i] = i * SUBCAP;           // (xcd*256+bin) region bases
  else if (i < 4096) gcur2[i - 2048] = (i - 2048) * SUBCAP;
  if (i == 4096) out[0] = (float)n * bv2[0];
}

// Single-pass coarse partition with XCD-private bucket regions (R11: keeps
// partial-line stores merging in the local L2; cross-XCD sharing caused 4x
// write-through amplification).
__global__ __launch_bounds__(256) void partition_kernel(
    const int* __restrict__ src, const int* __restrict__ dst,
    int* __restrict__ gcur1, int* __restrict__ gcur2,
    unsigned int* __restrict__ part, unsigned short* __restrict__ part_s, int ne) {
  __shared__ int h1[256], h2[256], c1[256], c2[256];
  int t = threadIdx.x, b = blockIdx.x;
  h1[t] = 0; h2[t] = 0;
  __syncthreads();
  int base = b * TILE;
  int lim = min(base + TILE, ne);
  for (int i = base + t; i < lim; i += 256) {
    atomicAdd(&h1[((unsigned)dst[i]) >> 8], 1);
    atomicAdd(&h2[((unsigned)src[i]) >> 8], 1);
  }
  __syncthreads();
  int xcd = xcc_id();
  c1[t] = atomicAdd(&gcur1[xcd * 256 + t], h1[t]);
  c2[t] = atomicAdd(&gcur2[xcd * 256 + t], h2[t]);
  __syncthreads();
  for (int i = base + t; i < lim; i += 256) {
    unsigned d = (unsigned)dst[i], s = (unsigned)src[i];
    int p1 = atomicAdd(&c1[d >> 8], 1);
    part[p1] = (d << 16) | s;
    int p2 = atomicAdd(&c2[s >> 8], 1);
    part_s[p2] = (unsigned short)s;
  }
}

// Split bucket pass (512 blocks = 2/CU): b<256 dst side (indeg/deg/row_beg,
// csr scatter at dense base b*8192); b>=256 src side (outdeg hist).
__global__ __launch_bounds__(256) void bucket_kernel(
    const unsigned int* __restrict__ part, const unsigned short* __restrict__ part_s,
    const int* __restrict__ gcur1, const int* __restrict__ gcur2,
    int* __restrict__ row_beg, int* __restrict__ deg, int* __restrict__ csr_src,
    int* __restrict__ outdeg, int n) {
  __shared__ int h[256], sc[256], c[256];
  int t = threadIdx.x;
  int b = blockIdx.x;
  h[t] = 0;
  __syncthreads();
  if (b < 256) {
#pragma unroll
    for (int xz = 0; xz < 8; xz++) {
      int rb = (xz * 256 + b) * SUBCAP, re = gcur1[xz * 256 + b];
      for (int i = rb + t; i < re; i += 256)
        atomicAdd(&h[(part[i] >> 16) & 255], 1);
    }
    __syncthreads();
    int hv = h[t];
    sc[t] = hv;
    __syncthreads();
    for (int off = 1; off < 256; off <<= 1) {
      int u = (t >= off) ? sc[t - off] : 0;
      __syncthreads();
      sc[t] += u;
      __syncthreads();
    }
    int bucketBase = b * 8192;
    int excl = sc[t] - hv;
    int node = b * 256 + t;
    if (node < n) { row_beg[node] = bucketBase + excl; deg[node] = hv; }
    c[t] = bucketBase + excl;
    __syncthreads();
#pragma unroll
    for (int xz = 0; xz < 8; xz++) {
      int rb = (xz * 256 + b) * SUBCAP, re = gcur1[xz * 256 + b];
      for (int i = rb + t; i < re; i += 256) {
        unsigned key = part[i];
        int pos = atomicAdd(&c[(key >> 16) & 255], 1);
        csr_src[pos] = (int)(key & 0xFFFFu);
      }
    }
  } else {
    int bs = b - 256;
#pragma unroll
    for (int xz = 0; xz < 8; xz++) {
      int sb = (xz * 256 + bs) * SUBCAP, se = gcur2[xz * 256 + bs];
      for (int i = sb + t; i < se; i += 256)
        atomicAdd(&h[part_s[i] & 255], 1);
    }
    __syncthreads();
    int node = bs * 256 + t;
    if (node < n) outdeg[node] = h[t];
  }
}

// p2[i] = rsqrt(indeg+1) * [x_i, outdeg_i]  (needs both halves of bucket pass)
__global__ void p2_kernel(const float* __restrict__ x, const int* __restrict__ outdeg,
                          const int* __restrict__ deg, float* __restrict__ p2, int n) {
  int i = blockIdx.x * blockDim.x + threadIdx.x;
  if (i < n) {
    float dinv = rsqrtf((float)deg[i] + 1.0f);
    p2[2 * i]     = dinv * x[i];
    p2[2 * i + 1] = dinv * (float)outdeg[i];
  }
}

// GCN aggregate in 2-dim space: t[d] = dinv*(sum_in dinv[s]*xin[s] + self).
// 16 lanes per node (mean deg 32 -> ~2 iters), 4 nodes/wave.
__global__ __launch_bounds__(256) void gcn_t_kernel(
    const int* __restrict__ row_beg, const int* __restrict__ deg,
    const int* __restrict__ csr_src,
    const float* __restrict__ p2, float2* __restrict__ tvec, int npad, int n) {
  int tid = threadIdx.x;
  int lane = tid & 63;
  int sl = lane & 15, g = lane >> 4;
  int wid = blockIdx.x * 16 + (tid >> 6) * 4 + g;
  if (wid >= npad) return;
  int beg = 0, dg = 0;
  if (wid < n) { beg = row_beg[wid]; dg = deg[wid]; }
  float s0 = 0.0f, s1 = 0.0f;
  for (int k = beg + sl; k < beg + dg; k += 16) {
    int s = csr_src[k];
    float2 v = *reinterpret_cast<const float2*>(p2 + 2 * (size_t)s);
    s0 += v.x; s1 += v.y;
  }
#pragma unroll
  for (int off = 1; off < 16; off <<= 1) {
    s0 += __shfl_xor(s0, off, 64);
    s1 += __shfl_xor(s1, off, 64);
  }
  if (sl == 0) {
    if (wid < n) {
      float dinv = rsqrtf((float)dg + 1.0f);
      float2 self = *reinterpret_cast<const float2*>(p2 + 2 * (size_t)wid);
      tvec[wid] = make_float2(dinv * (s0 + self.x), dinv * (s1 + self.y));
    } else {
      tvec[wid] = make_float2(0.f, 0.f);
    }
  }
}

// SAGE mean, two-phase (plain fmaf — pk_fma asm and fdot2 both regressed):
// block = 32 dst nodes. Phase A: lane-parallel gather of the group's edge
// t-pairs into LDS. Phase B: wave w owns 8 nodes; lane owns channels 2l,2l+1;
// recompute a1[src] from LDS-broadcast t + 8 VALU/edge, register accumulate.
__global__ __launch_bounds__(256) void sage_kernel(
    const int* __restrict__ row_beg, const int* __restrict__ deg,
    const int* __restrict__ csr_src, const float2* __restrict__ tvec,
    const float* __restrict__ Wg, const float* __restrict__ bg,
    unsigned int* __restrict__ agg32, int n) {
  __shared__ float2 sE[SCHUNK];
  __shared__ int sR[SNODES + 1];
  int tid = threadIdx.x, lane = tid & 63, w = tid >> 6;
  int node0 = blockIdx.x * SNODES;
  if (tid <= SNODES) {
    int node = node0 + tid;
    int v;
    if (tid == SNODES) {
      int last = min(node, n) - 1;
      v = (last >= 0) ? row_beg[last] + deg[last] : 0;
    } else if (node < n) {
      v = row_beg[node];
    } else {
      v = (n > 0) ? row_beg[n - 1] + deg[n - 1] : 0;
    }
    sR[tid] = v;
  }
  __syncthreads();
  int base = sR[0], endAll = sR[SNODES];

  int c0 = 2 * lane, c1 = c0 + 1;
  float w00 = Wg[c0], w10 = Wg[NCH + c0], b0 = bg[c0];
  float w01 = Wg[c1], w11 = Wg[NCH + c1], b1 = bg[c1];
  float ax[8], ay[8];
#pragma unroll
  for (int i = 0; i < 8; i++) { ax[i] = 0.f; ay[i] = 0.f; }

  for (int cbeg = base; cbeg < endAll; cbeg += SCHUNK) {
    int cend = min(cbeg + SCHUNK, endAll);
    __syncthreads();
    for (int k = cbeg + tid; k < cend; k += 256)
      sE[k - cbeg] = tvec[csr_src[k]];
    __syncthreads();
#pragma unroll
    for (int i = 0; i < 8; i++) {
      int nd = w * 8 + i;
      int rb = max(sR[nd], cbeg) - cbeg;
      int re = min(sR[nd + 1], cend) - cbeg;
      int k = rb;
      for (; k + 3 < re; k += 4) {
        float2 tA = sE[k], tB = sE[k + 1], tC = sE[k + 2], tD = sE[k + 3];
        ax[i] += fmaxf(fmaf(tA.x, w00, fmaf(tA.y, w10, b0)), 0.f)
               + fmaxf(fmaf(tB.x, w00, fmaf(tB.y, w10, b0)), 0.f)
               + fmaxf(fmaf(tC.x, w00, fmaf(tC.y, w10, b0)), 0.f)
               + fmaxf(fmaf(tD.x, w00, fmaf(tD.y, w10, b0)), 0.f);
        ay[i] += fmaxf(fmaf(tA.x, w01, fmaf(tA.y, w11, b1)), 0.f)
               + fmaxf(fmaf(tB.x, w01, fmaf(tB.y, w11, b1)), 0.f)
               + fmaxf(fmaf(tC.x, w01, fmaf(tC.y, w11, b1)), 0.f)
               + fmaxf(fmaf(tD.x, w01, fmaf(tD.y, w11, b1)), 0.f);
      }
      for (; k < re; k++) {
        float2 tA = sE[k];
        ax[i] += fmaxf(fmaf(tA.x, w00, fmaf(tA.y, w10, b0)), 0.f);
        ay[i] += fmaxf(fmaf(tA.x, w01, fmaf(tA.y, w11, b1)), 0.f);
      }
    }
  }
#pragma unroll
  for (int i = 0; i < 8; i++) {
    int nd = w * 8 + i;
    int cnt = sR[nd + 1] - sR[nd];
    float inv = 1.0f / (float)(cnt > 1 ? cnt : 1);
    agg32[(size_t)(node0 + nd) * 64 + lane] =
        (unsigned int)f2bf(ax[i] * inv) | ((unsigned int)f2bf(ay[i] * inv) << 16);
  }
}

// MFMA head: A = [agg | a1] (a1 recomputed from t in LDS), K=256 GEMM vs
// [Wl;Wr], bias, bf16, K=128 GEMM vs Wv1, relu, dot Wv2, reduce-sum.
__global__ __launch_bounds__(256) void head_kernel(
    const unsigned short* __restrict__ agg, const float2* __restrict__ tvec,
    const float* __restrict__ Wg, const float* __restrict__ bg,
    const unsigned short* __restrict__ fw1, const unsigned short* __restrict__ fw2,
    const float* __restrict__ bl, const float* __restrict__ bv1,
    const float* __restrict__ Wv2, float* __restrict__ out, int n) {
  __shared__ __align__(16) unsigned short sA[64 * HSTRIDE];  // 33 KB
  __shared__ float sT[128];
  __shared__ float sRed[4];
  int tid = threadIdx.x;
  int lane = tid & 63;
  int w = tid >> 6;
  int m16 = lane & 15;
  int quad = lane >> 4;
  int node0 = blockIdx.x * 64;

  const uint4* g = reinterpret_cast<const uint4*>(agg + (size_t)node0 * NCH);
  for (int c = tid; c < 1024; c += 256) {
    int row = c >> 4, off = c & 15;
    *reinterpret_cast<uint4*>(&sA[row * HSTRIDE + off * 8]) = g[row * 16 + off];
  }
  if (tid < 128) sT[tid] = reinterpret_cast<const float*>(tvec + node0)[tid];
  __syncthreads();

  {
    int cp = tid & 63, r0 = tid >> 6;
    int c0 = 2 * cp, c1 = c0 + 1;
    float w00 = Wg[c0], w10 = Wg[NCH + c0], b0 = bg[c0];
    float w01 = Wg[c1], w11 = Wg[NCH + c1], b1 = bg[c1];
#pragma unroll
    for (int i = 0; i < 16; i++) {
      int row = r0 + 4 * i;
      float t0 = sT[2 * row], t1 = sT[2 * row + 1];
      float z0 = fmaxf(fmaf(t0, w00, fmaf(t1, w10, b0)), 0.f);
      float z1 = fmaxf(fmaf(t0, w01, fmaf(t1, w11, b1)), 0.f);
      *reinterpret_cast<unsigned int*>(&sA[row * HSTRIDE + 128 + 2 * cp]) =
          (unsigned int)f2bf(z0) | ((unsigned int)f2bf(z1) << 16);
    }
  }

  bf16x8 b1f[2][8];
  const bf16x8* f1 = reinterpret_cast<const bf16x8*>(fw1);
#pragma unroll
  for (int p = 0; p < 2; p++)
#pragma unroll
    for (int s = 0; s < 8; s++)
      b1f[p][s] = f1[((w * 2 + p) * 8 + s) * 64 + lane];

  f32x4 acc[4][2];
#pragma unroll
  for (int mt = 0; mt < 4; mt++)
#pragma unroll
    for (int p = 0; p < 2; p++) acc[mt][p] = (f32x4)0.0f;

  __syncthreads();

#pragma unroll
  for (int s = 0; s < 8; s++) {
#pragma unroll
    for (int mt = 0; mt < 4; mt++) {
      bf16x8 aF = *reinterpret_cast<const bf16x8*>(
          &sA[(mt * 16 + m16) * HSTRIDE + s * 32 + quad * 8]);
#pragma unroll
      for (int p = 0; p < 2; p++)
        acc[mt][p] = __builtin_amdgcn_mfma_f32_16x16x32_bf16(aF, b1f[p][s],
                                                             acc[mt][p], 0, 0, 0);
    }
  }

  float blv[2];
#pragma unroll
  for (int p = 0; p < 2; p++) blv[p] = bl[(w * 2 + p) * 16 + m16];
  __syncthreads();
#pragma unroll
  for (int mt = 0; mt < 4; mt++)
#pragma unroll
    for (int p = 0; p < 2; p++) {
      int col = (w * 2 + p) * 16 + m16;
#pragma unroll
      for (int r = 0; r < 4; r++) {
        int row = mt * 16 + quad * 4 + r;
        sA[row * HSTRIDE + col] = f2bf(acc[mt][p][r] + blv[p]);
      }
    }
  __syncthreads();

  bf16x8 b2f[4];
  const bf16x8* f2 = reinterpret_cast<const bf16x8*>(fw2);
#pragma unroll
  for (int s = 0; s < 4; s++) b2f[s] = f2[(w * 4 + s) * 64 + lane];

  f32x4 acc2[4];
#pragma unroll
  for (int mt = 0; mt < 4; mt++) acc2[mt] = (f32x4)0.0f;

#pragma unroll
  for (int s = 0; s < 4; s++) {
#pragma unroll
    for (int mt = 0; mt < 4; mt++) {
      bf16x8 aF = *reinterpret_cast<const bf16x8*>(
          &sA[(mt * 16 + m16) * HSTRIDE + s * 32 + quad * 8]);
      acc2[mt] = __builtin_amdgcn_mfma_f32_16x16x32_bf16(aF, b2f[s], acc2[mt], 0, 0, 0);
    }
  }

  int c2 = w * 16 + m16;
  float bvj = bv1[c2], w2 = Wv2[c2];
  float vsum = 0.0f;
#pragma unroll
  for (int mt = 0; mt < 4; mt++)
#pragma unroll
    for (int r = 0; r < 4; r++) {
      int node = node0 + mt * 16 + quad * 4 + r;
      if (node < n) vsum += fmaxf(acc2[mt][r] + bvj, 0.0f) * w2;
    }
#pragma unroll
  for (int off = 1; off < 64; off <<= 1) vsum += __shfl_xor(vsum, off, 64);
  if (lane == 0) sRed[w] = vsum;
  __syncthreads();
  if (tid == 0) atomicAdd(out, sRed[0] + sRed[1] + sRed[2] + sRed[3]);
}

extern "C" void kernel_launch(void* const* d_in, const int* in_sizes, int n_in,
                              void* d_out, int out_size, void* d_ws, size_t ws_size,
                              hipStream_t stream) {
  const float* x   = (const float*)d_in[0];
  const int*   ei  = (const int*)d_in[1];
  const float* Wg  = (const float*)d_in[2];
  const float* bg  = (const float*)d_in[3];
  const float* Wl  = (const float*)d_in[4];
  const float* bl  = (const float*)d_in[5];
  const float* Wr  = (const float*)d_in[6];
  const float* Wv1 = (const float*)d_in[7];
  const float* bv1 = (const float*)d_in[8];
  const float* Wv2 = (const float*)d_in[9];
  const float* bv2 = (const float*)d_in[10];
  float* out = (float*)d_out;

  int n  = in_sizes[0];
  int E_ = in_sizes[1] / 2;
  int npad = ((n + 63) / 64) * 64;
  int B1 = (E_ + TILE - 1) / TILE;
  const int* src = ei;
  const int* dst = ei + E_;

  // workspace layout (16B alignment per region)
  char* base = (char*)d_ws;
  unsigned short* agg = (unsigned short*)base;  base += (size_t)npad * NCH * 2;   // 12.8MB
  float2* tvec    = (float2*)base;              base += (size_t)npad * 8;
  unsigned short* fw1 = (unsigned short*)base;  base += 32768 * 2;
  unsigned short* fw2 = (unsigned short*)base;  base += 8192 * 2;
  float* p2       = (float*)base;               base += (size_t)n * 2 * 4;
  int* gcur1      = (int*)base;                 base += 2048 * 4;
  int* gcur2      = (int*)base;                 base += 2048 * 4;
  unsigned int* part = (unsigned int*)base;     base += (size_t)2048 * SUBCAP * 4;  // 25.2MB
  int* row_beg    = (int*)base;                 base += (size_t)n * 4;
  int* deg        = (int*)base;                 base += (size_t)n * 4;
  int* outdeg     = (int*)base;                 base += (size_t)n * 4;
  int* csr_src    = (int*)base;                 base += (size_t)256 * 8192 * 4;     // 8.4MB
  unsigned short* part_s = (unsigned short*)base;  // 2048*SUBCAP*2 = 12.6MB

  prep_w_kernel<<<128, 256, 0, stream>>>(Wl, Wr, Wv1, fw1, fw2, gcur1, gcur2,
                                         out, bv2, n);
  partition_kernel<<<B1, 256, 0, stream>>>(src, dst, gcur1, gcur2, part, part_s, E_);
  bucket_kernel<<<512, 256, 0, stream>>>(part, part_s, gcur1, gcur2,
                                         row_beg, deg, csr_src, outdeg, n);
  p2_kernel<<<(n + 255) / 256, 256, 0, stream>>>(x, outdeg, deg, p2, n);

  gcn_t_kernel<<<npad / 16, 256, 0, stream>>>(row_beg, deg, csr_src, p2,
                                              tvec, npad, n);
  sage_kernel<<<npad / SNODES, 256, 0, stream>>>(row_beg, deg, csr_src, tvec,
                                                 Wg, bg, (unsigned int*)agg, n);
  head_kernel<<<npad / 64, 256, 0, stream>>>(agg, tvec, Wg, bg, fw1, fw2,
                                             bl, bv1, Wv2, out, n);
}